// Round 2
// baseline (112.965 us; speedup 1.0000x reference)
//
#include <hip/hip_runtime.h>
#include <hip/hip_bf16.h>

// B=32, N=64, D=128, H=256
typedef __attribute__((ext_vector_type(8))) _Float16 half8;
typedef __attribute__((ext_vector_type(4))) float f32x4;

// ---------------------------------------------------------------------------
// Prep: blocks 0..127  : L/R = objects @ gW1(top/bottom), 16 rows each.
//         Lh = fp16(L + gb1)  [row][k] linear
//         Rh = fp16(R)        [row] rows of 512B, 16B-units XOR-swizzled:
//                             byte = row*512 + (2k ^ ((row&15)<<4))
//       blocks 128..143: transpose gW2 -> W2h[col][k] fp16
//       block  144     : zero S
// ---------------------------------------------------------------------------
__global__ __launch_bounds__(256) void rn_prep(
    const float* __restrict__ obj, const float* __restrict__ gW1,
    const float* __restrict__ gb1, const float* __restrict__ gW2,
    _Float16* __restrict__ Lh, char* __restrict__ RhB,
    _Float16* __restrict__ W2h, float* __restrict__ S)
{
    __shared__ float so[16 * 128];
    __shared__ float tt[64 * 65];
    const int blk = blockIdx.x, t = threadIdx.x;

    if (blk < 128) {
        const int r0 = blk * 16;
        for (int it = 0; it < 8; ++it) so[it * 256 + t] = obj[r0 * 128 + it * 256 + t];
        __syncthreads();
        float accL[16], accR[16];
        #pragma unroll
        for (int r = 0; r < 16; ++r) { accL[r] = 0.f; accR[r] = 0.f; }
        for (int k = 0; k < 128; ++k) {
            float wL = gW1[k * 256 + t];
            float wR = gW1[(128 + k) * 256 + t];
            #pragma unroll
            for (int r = 0; r < 16; ++r) {
                float o = so[r * 128 + k];
                accL[r] += o * wL;
                accR[r] += o * wR;
            }
        }
        float bb = gb1[t];
        #pragma unroll
        for (int r = 0; r < 16; ++r) {
            int row = r0 + r;
            Lh[row * 256 + t] = (_Float16)(accL[r] + bb);
            *(_Float16*)(RhB + row * 512 + ((2 * t) ^ ((row & 15) << 4))) = (_Float16)accR[r];
        }
    } else if (blk < 144) {
        const int tb = blk - 128;
        const int k0 = (tb >> 2) * 64, c0 = (tb & 3) * 64;
        for (int it = 0; it < 16; ++it) {
            int idx = it * 256 + t, rr = idx >> 6, cc = idx & 63;
            tt[rr * 65 + cc] = gW2[(k0 + rr) * 256 + c0 + cc];
        }
        __syncthreads();
        for (int it = 0; it < 16; ++it) {
            int idx = it * 256 + t, cr = idx >> 6, kk = idx & 63;
            W2h[(c0 + cr) * 256 + (k0 + kk)] = (_Float16)tt[kk * 65 + cr];
        }
    } else {
        for (int it = 0; it < 32; ++it) S[it * 256 + t] = 0.f;
    }
}

// ---------------------------------------------------------------------------
// Main: block = (b, ig of 4 i's). 4 waves, wave w owns cols [w*64, w*64+64).
// W2 frags live in registers (loaded once). Rh[b] (swizzled) + Lh rows in LDS.
// A-frag built in regs: pk_max(pk_add(lh, rh), 0). mfma_f32_16x16x32_f16.
// Column sums accumulated across i in regs, one atomicAdd per col at the end.
// ---------------------------------------------------------------------------
__global__ __launch_bounds__(256, 2) void rn_main(
    const char* __restrict__ LhB, const char* __restrict__ RhB,
    const _Float16* __restrict__ W2h, const float* __restrict__ gb2,
    float* __restrict__ S)
{
    __shared__ __attribute__((aligned(16))) char smem[34816];  // Rh 32KB + Lh 2KB
    const int blk = blockIdx.x;               // 512 = 32 b x 16 ig
    const int b = blk >> 4, ig = blk & 15;
    const int t = threadIdx.x, lane = t & 63, w = t >> 6;
    const int lc = lane & 15, lg = lane >> 4;

    {   // stage Rh[b] (pre-swizzled, linear copy) + Lh rows ig*4..+4
        const char* gR = RhB + b * 32768;
        #pragma unroll
        for (int it = 0; it < 8; ++it) {
            int u = it * 256 + t;
            *(f32x4*)(smem + u * 16) = *(const f32x4*)(gR + u * 16);
        }
        if (t < 128) {
            const char* gL = LhB + (b * 64 + ig * 4) * 512;
            *(f32x4*)(smem + 32768 + t * 16) = *(const f32x4*)(gL + t * 16);
        }
    }
    __syncthreads();

    // per-wave register-resident B: 4 n-tiles x 8 k-steps
    half8 bfr[4][8];
    #pragma unroll
    for (int n = 0; n < 4; ++n)
        #pragma unroll
        for (int ks = 0; ks < 8; ++ks)
            bfr[n][ks] = *(const half8*)(W2h + (w * 64 + n * 16 + lc) * 256 + ks * 32 + lg * 8);

    float bias[4];
    #pragma unroll
    for (int n = 0; n < 4; ++n) bias[n] = gb2[w * 64 + n * 16 + lc];

    float csum[4] = {0.f, 0.f, 0.f, 0.f};
    const half8 zero8 = {(_Float16)0.f, (_Float16)0.f, (_Float16)0.f, (_Float16)0.f,
                         (_Float16)0.f, (_Float16)0.f, (_Float16)0.f, (_Float16)0.f};

    for (int ii = 0; ii < 4; ++ii) {
        f32x4 acc[4][4];
        #pragma unroll
        for (int m = 0; m < 4; ++m)
            #pragma unroll
            for (int n = 0; n < 4; ++n)
                acc[m][n] = (f32x4){0.f, 0.f, 0.f, 0.f};

        #pragma unroll
        for (int ks = 0; ks < 8; ++ks) {
            const int kb = ks * 64 + lg * 16;   // byte offset of this lane's k-group
            half8 lh = *(const half8*)(smem + 32768 + ii * 512 + kb);
            #pragma unroll
            for (int m = 0; m < 4; ++m) {
                int row = m * 16 + lc;
                half8 rh = *(const half8*)(smem + row * 512 + (kb ^ (lc << 4)));
                half8 av = lh + rh;                               // v_pk_add_f16
                av = __builtin_elementwise_max(av, zero8);        // v_pk_max_f16
                #pragma unroll
                for (int n = 0; n < 4; ++n)
                    acc[m][n] = __builtin_amdgcn_mfma_f32_16x16x32_f16(
                        av, bfr[n][ks], acc[m][n], 0, 0, 0);
            }
        }

        const int iglob = ig * 4 + ii;
        #pragma unroll
        for (int n = 0; n < 4; ++n) {
            float cs = 0.f;
            #pragma unroll
            for (int m = 0; m < 4; ++m)
                #pragma unroll
                for (int q = 0; q < 4; ++q) {
                    int row = m * 16 + lg * 4 + q;   // = j
                    float v = fmaxf(acc[m][n][q] + bias[n], 0.f);
                    cs += (row == iglob) ? 0.f : v;
                }
            csum[n] += cs;
        }
    }

    #pragma unroll
    for (int n = 0; n < 4; ++n) {
        float cs = csum[n];
        cs += __shfl_xor(cs, 16);
        cs += __shfl_xor(cs, 32);
        if (lane < 16) atomicAdd(&S[b * 256 + w * 64 + n * 16 + lc], cs);
    }
}

// ---------------------------------------------------------------------------
// Final: block per b, 1024 threads = (col 256) x (kq 4). Three chained
// matvecs with k split 4-way + LDS reduce.
// ---------------------------------------------------------------------------
__global__ __launch_bounds__(1024) void rn_final(
    const float* __restrict__ S, const float* __restrict__ gW3,
    const float* __restrict__ gb3, const float* __restrict__ fW1,
    const float* __restrict__ fb1, const float* __restrict__ fW2,
    const float* __restrict__ fb2, float* __restrict__ out)
{
    __shared__ float vec[256];
    __shared__ float ps[4][256];
    const int b = blockIdx.x, t = threadIdx.x;
    const int col = t & 255, kq = t >> 8;

    if (kq == 0) vec[col] = S[b * 256 + col];
    __syncthreads();

    // phase 1: agg = vec @ gW3 + 4032*gb3
    {
        float s = 0.f;
        #pragma unroll 16
        for (int kk = 0; kk < 64; ++kk) {
            int k = kq * 64 + kk;
            s += vec[k] * gW3[k * 256 + col];
        }
        ps[kq][col] = s;
    }
    __syncthreads();
    if (kq == 0)
        vec[col] = ps[0][col] + ps[1][col] + ps[2][col] + ps[3][col] + 4032.0f * gb3[col];
    __syncthreads();

    // phase 2: u = relu(vec @ fW1 + fb1)
    {
        float s = 0.f;
        #pragma unroll 16
        for (int kk = 0; kk < 64; ++kk) {
            int k = kq * 64 + kk;
            s += vec[k] * fW1[k * 256 + col];
        }
        ps[kq][col] = s;
    }
    __syncthreads();
    if (kq == 0)
        vec[col] = fmaxf(ps[0][col] + ps[1][col] + ps[2][col] + ps[3][col] + fb1[col], 0.f);
    __syncthreads();

    // phase 3: out = vec @ fW2 + fb2
    {
        float s = 0.f;
        #pragma unroll 16
        for (int kk = 0; kk < 64; ++kk) {
            int k = kq * 64 + kk;
            s += vec[k] * fW2[k * 256 + col];
        }
        ps[kq][col] = s;
    }
    __syncthreads();
    if (kq == 0)
        out[b * 256 + col] = ps[0][col] + ps[1][col] + ps[2][col] + ps[3][col] + fb2[col];
}

extern "C" void kernel_launch(void* const* d_in, const int* in_sizes, int n_in,
                              void* d_out, int out_size, void* d_ws, size_t ws_size,
                              hipStream_t stream)
{
    const float* obj = (const float*)d_in[0];
    const float* gW1 = (const float*)d_in[1];
    const float* gb1 = (const float*)d_in[2];
    const float* gW2 = (const float*)d_in[3];
    const float* gb2 = (const float*)d_in[4];
    const float* gW3 = (const float*)d_in[5];
    const float* gb3 = (const float*)d_in[6];
    const float* fW1 = (const float*)d_in[7];
    const float* fb1 = (const float*)d_in[8];
    const float* fW2 = (const float*)d_in[9];
    const float* fb2 = (const float*)d_in[10];
    float* out = (float*)d_out;

    char* ws = (char*)d_ws;
    _Float16* Lh  = (_Float16*)(ws);                     // 2048*256*2 = 1 MB
    char*     RhB = ws + (1u << 20);                     // 1 MB (swizzled fp16)
    _Float16* W2h = (_Float16*)(ws + (2u << 20));        // 128 KB
    float*    S   = (float*)(ws + (2u << 20) + (128u << 10));  // 32 KB

    rn_prep <<<145, 256, 0, stream>>>(obj, gW1, gb1, gW2, Lh, RhB, W2h, S);
    rn_main <<<512, 256, 0, stream>>>((const char*)Lh, RhB, W2h, gb2, S);
    rn_final<<<32, 1024, 0, stream>>>(S, gW3, gb3, fW1, fb1, fW2, fb2, out);
}

// Round 3
// 63.570 us; speedup vs baseline: 1.7770x; 1.7770x over previous
//
#include <hip/hip_runtime.h>
#include <hip/hip_bf16.h>

// B=32, N=64, D=128, H=256
typedef __attribute__((ext_vector_type(8))) _Float16 half8;
typedef __attribute__((ext_vector_type(4))) float f32x4;

// ---------------------------------------------------------------------------
// Prep: blocks 0..127  : L/R = objects @ gW1(top/bottom), 16 rows each.
//         Lh = fp16(L + gb1)  [row][k] linear (512B rows)
//         Rh = fp16(R)        rows of 512B, 16B-units XOR-swizzled:
//                             byte = row*512 + (2k ^ ((row&15)<<4))
//       blocks 128..143: transpose gW2 -> W2h[col][k] fp16
//       block  144     : zero S
// ---------------------------------------------------------------------------
__global__ __launch_bounds__(256) void rn_prep(
    const float* __restrict__ obj, const float* __restrict__ gW1,
    const float* __restrict__ gb1, const float* __restrict__ gW2,
    _Float16* __restrict__ Lh, char* __restrict__ RhB,
    _Float16* __restrict__ W2h, float* __restrict__ S)
{
    __shared__ float so[16 * 128];
    __shared__ float tt[64 * 65];
    const int blk = blockIdx.x, t = threadIdx.x;

    if (blk < 128) {
        const int r0 = blk * 16;
        for (int it = 0; it < 8; ++it) so[it * 256 + t] = obj[r0 * 128 + it * 256 + t];
        __syncthreads();
        float accL[16], accR[16];
        #pragma unroll
        for (int r = 0; r < 16; ++r) { accL[r] = 0.f; accR[r] = 0.f; }
        for (int k = 0; k < 128; ++k) {
            float wL = gW1[k * 256 + t];
            float wR = gW1[(128 + k) * 256 + t];
            #pragma unroll
            for (int r = 0; r < 16; ++r) {
                float o = so[r * 128 + k];
                accL[r] += o * wL;
                accR[r] += o * wR;
            }
        }
        float bb = gb1[t];
        #pragma unroll
        for (int r = 0; r < 16; ++r) {
            int row = r0 + r;
            Lh[row * 256 + t] = (_Float16)(accL[r] + bb);
            *(_Float16*)(RhB + row * 512 + ((2 * t) ^ ((row & 15) << 4))) = (_Float16)accR[r];
        }
    } else if (blk < 144) {
        const int tb = blk - 128;
        const int k0 = (tb >> 2) * 64, c0 = (tb & 3) * 64;
        for (int it = 0; it < 16; ++it) {
            int idx = it * 256 + t, rr = idx >> 6, cc = idx & 63;
            tt[rr * 65 + cc] = gW2[(k0 + rr) * 256 + c0 + cc];
        }
        __syncthreads();
        for (int it = 0; it < 16; ++it) {
            int idx = it * 256 + t, cr = idx >> 6, kk = idx & 63;
            W2h[(c0 + cr) * 256 + (k0 + kk)] = (_Float16)tt[kk * 65 + cr];
        }
    } else {
        for (int it = 0; it < 32; ++it) S[it * 256 + t] = 0.f;
    }
}

// ---------------------------------------------------------------------------
// Main: grid 256 = 32 b x 8 ig; block 256 thr = 4 waves; 8 i's per block.
// Wave w owns cols [w*64, w*64+64), W2 slice register-resident (128 VGPR),
// loaded ONCE per block, reused across 8 i's. Rh[b] (32KB, pre-swizzled) +
// 8 Lh rows (4KB) staged in LDS once. A-frag built in regs:
// pk_max(pk_add(lh, rh), 0); mfma_f32_16x16x32_f16. Column sums accumulated
// across all 8 i's in regs; one atomicAdd per col at the end.
// NO occupancy bound -> compiler free to use ~240 VGPRs, zero spill.
// ---------------------------------------------------------------------------
__global__ __launch_bounds__(256) void rn_main(
    const char* __restrict__ LhB, const char* __restrict__ RhB,
    const _Float16* __restrict__ W2h, const float* __restrict__ gb2,
    float* __restrict__ S)
{
    __shared__ __attribute__((aligned(16))) char smem[36864];  // Rh 32KB + Lh 4KB
    const int blk = blockIdx.x;               // 256 = 32 b x 8 ig
    const int b = blk >> 3, ig = blk & 7;
    const int t = threadIdx.x, lane = t & 63, w = t >> 6;
    const int lc = lane & 15, lg = lane >> 4;

    {   // stage Rh[b] (pre-swizzled, linear copy) + Lh rows ig*8..+8
        const char* gR = RhB + b * 32768;
        #pragma unroll
        for (int it = 0; it < 8; ++it) {
            int u = it * 256 + t;
            *(f32x4*)(smem + u * 16) = *(const f32x4*)(gR + u * 16);
        }
        const char* gL = LhB + (b * 64 + ig * 8) * 512;
        *(f32x4*)(smem + 32768 + t * 16) = *(const f32x4*)(gL + t * 16);
    }
    __syncthreads();

    // per-wave register-resident B: 4 n-tiles x 8 k-steps (128 VGPRs)
    half8 bfr[4][8];
    #pragma unroll
    for (int n = 0; n < 4; ++n)
        #pragma unroll
        for (int ks = 0; ks < 8; ++ks)
            bfr[n][ks] = *(const half8*)(W2h + (w * 64 + n * 16 + lc) * 256 + ks * 32 + lg * 8);

    float bias[4];
    #pragma unroll
    for (int n = 0; n < 4; ++n) bias[n] = gb2[w * 64 + n * 16 + lc];

    float csum[4] = {0.f, 0.f, 0.f, 0.f};
    const half8 zero8 = {(_Float16)0.f, (_Float16)0.f, (_Float16)0.f, (_Float16)0.f,
                         (_Float16)0.f, (_Float16)0.f, (_Float16)0.f, (_Float16)0.f};

    for (int ii = 0; ii < 8; ++ii) {
        f32x4 acc[4][4];
        #pragma unroll
        for (int m = 0; m < 4; ++m)
            #pragma unroll
            for (int n = 0; n < 4; ++n)
                acc[m][n] = (f32x4){0.f, 0.f, 0.f, 0.f};

        #pragma unroll
        for (int ks = 0; ks < 8; ++ks) {
            const int kb = ks * 64 + lg * 16;   // byte offset of this lane's k-group
            half8 lh = *(const half8*)(smem + 32768 + ii * 512 + kb);
            #pragma unroll
            for (int m = 0; m < 4; ++m) {
                int row = m * 16 + lc;
                half8 rh = *(const half8*)(smem + row * 512 + (kb ^ (lc << 4)));
                half8 av = lh + rh;                               // v_pk_add_f16
                av = __builtin_elementwise_max(av, zero8);        // v_pk_max_f16
                #pragma unroll
                for (int n = 0; n < 4; ++n)
                    acc[m][n] = __builtin_amdgcn_mfma_f32_16x16x32_f16(
                        av, bfr[n][ks], acc[m][n], 0, 0, 0);
            }
        }

        const int iglob = ig * 8 + ii;
        #pragma unroll
        for (int n = 0; n < 4; ++n) {
            float cs = 0.f;
            #pragma unroll
            for (int m = 0; m < 4; ++m)
                #pragma unroll
                for (int q = 0; q < 4; ++q) {
                    int row = m * 16 + lg * 4 + q;   // = j
                    float v = fmaxf(acc[m][n][q] + bias[n], 0.f);
                    cs += (row == iglob) ? 0.f : v;
                }
            csum[n] += cs;
        }
    }

    #pragma unroll
    for (int n = 0; n < 4; ++n) {
        float cs = csum[n];
        cs += __shfl_xor(cs, 16);
        cs += __shfl_xor(cs, 32);
        if (lane < 16) atomicAdd(&S[b * 256 + w * 64 + n * 16 + lc], cs);
    }
}

// ---------------------------------------------------------------------------
// Final: block per b, 1024 threads = (col 256) x (kq 4). Three chained
// matvecs with k split 4-way + LDS reduce.
// ---------------------------------------------------------------------------
__global__ __launch_bounds__(1024) void rn_final(
    const float* __restrict__ S, const float* __restrict__ gW3,
    const float* __restrict__ gb3, const float* __restrict__ fW1,
    const float* __restrict__ fb1, const float* __restrict__ fW2,
    const float* __restrict__ fb2, float* __restrict__ out)
{
    __shared__ float vec[256];
    __shared__ float ps[4][256];
    const int b = blockIdx.x, t = threadIdx.x;
    const int col = t & 255, kq = t >> 8;

    if (kq == 0) vec[col] = S[b * 256 + col];
    __syncthreads();

    {
        float s = 0.f;
        #pragma unroll 16
        for (int kk = 0; kk < 64; ++kk) {
            int k = kq * 64 + kk;
            s += vec[k] * gW3[k * 256 + col];
        }
        ps[kq][col] = s;
    }
    __syncthreads();
    if (kq == 0)
        vec[col] = ps[0][col] + ps[1][col] + ps[2][col] + ps[3][col] + 4032.0f * gb3[col];
    __syncthreads();

    {
        float s = 0.f;
        #pragma unroll 16
        for (int kk = 0; kk < 64; ++kk) {
            int k = kq * 64 + kk;
            s += vec[k] * fW1[k * 256 + col];
        }
        ps[kq][col] = s;
    }
    __syncthreads();
    if (kq == 0)
        vec[col] = fmaxf(ps[0][col] + ps[1][col] + ps[2][col] + ps[3][col] + fb1[col], 0.f);
    __syncthreads();

    {
        float s = 0.f;
        #pragma unroll 16
        for (int kk = 0; kk < 64; ++kk) {
            int k = kq * 64 + kk;
            s += vec[k] * fW2[k * 256 + col];
        }
        ps[kq][col] = s;
    }
    __syncthreads();
    if (kq == 0)
        out[b * 256 + col] = ps[0][col] + ps[1][col] + ps[2][col] + ps[3][col] + fb2[col];
}

extern "C" void kernel_launch(void* const* d_in, const int* in_sizes, int n_in,
                              void* d_out, int out_size, void* d_ws, size_t ws_size,
                              hipStream_t stream)
{
    const float* obj = (const float*)d_in[0];
    const float* gW1 = (const float*)d_in[1];
    const float* gb1 = (const float*)d_in[2];
    const float* gW2 = (const float*)d_in[3];
    const float* gb2 = (const float*)d_in[4];
    const float* gW3 = (const float*)d_in[5];
    const float* gb3 = (const float*)d_in[6];
    const float* fW1 = (const float*)d_in[7];
    const float* fb1 = (const float*)d_in[8];
    const float* fW2 = (const float*)d_in[9];
    const float* fb2 = (const float*)d_in[10];
    float* out = (float*)d_out;

    char* ws = (char*)d_ws;
    _Float16* Lh  = (_Float16*)(ws);                     // 1 MB
    char*     RhB = ws + (1u << 20);                     // 1 MB (swizzled fp16)
    _Float16* W2h = (_Float16*)(ws + (2u << 20));        // 128 KB
    float*    S   = (float*)(ws + (2u << 20) + (128u << 10));  // 32 KB

    rn_prep <<<145, 256, 0, stream>>>(obj, gW1, gb1, gW2, Lh, RhB, W2h, S);
    rn_main <<<256, 256, 0, stream>>>((const char*)Lh, RhB, W2h, gb2, S);
    rn_final<<<32, 1024, 0, stream>>>(S, gW3, gb3, fW1, fb1, fW2, fb2, out);
}

// Round 4
// 44.472 us; speedup vs baseline: 2.5402x; 1.4295x over previous
//
#include <hip/hip_runtime.h>
#include <hip/hip_bf16.h>

// B=32, N=64, D=128, H=256
typedef __attribute__((ext_vector_type(8))) _Float16 half8;
typedef __attribute__((ext_vector_type(4))) float f32x4;

// ---------------------------------------------------------------------------
// Prep: blocks 0..255  : L/R = objects @ gW1(top/bottom), 8 rows each.
//         Lh = fp16(L + gb1)  [row][k] linear (512B rows)
//         Rh = fp16(R)        rows of 512B, XOR-swizzled:
//                             byte = row*512 + (2k ^ ((row&15)<<4))
//       blocks 256..271: transpose gW2 -> W2h[col][k] fp16
//       block  272     : zero S
// ---------------------------------------------------------------------------
__global__ __launch_bounds__(256) void rn_prep(
    const float* __restrict__ obj, const float* __restrict__ gW1,
    const float* __restrict__ gb1, const float* __restrict__ gW2,
    _Float16* __restrict__ Lh, char* __restrict__ RhB,
    _Float16* __restrict__ W2h, float* __restrict__ S)
{
    __shared__ float so[8 * 128];
    __shared__ float tt[64 * 65];
    const int blk = blockIdx.x, t = threadIdx.x;

    if (blk < 256) {
        const int r0 = blk * 8;
        #pragma unroll
        for (int it = 0; it < 4; ++it) so[it * 256 + t] = obj[r0 * 128 + it * 256 + t];
        __syncthreads();
        float accL[8], accR[8];
        #pragma unroll
        for (int r = 0; r < 8; ++r) { accL[r] = 0.f; accR[r] = 0.f; }
        for (int k = 0; k < 128; ++k) {
            float wL = gW1[k * 256 + t];
            float wR = gW1[(128 + k) * 256 + t];
            #pragma unroll
            for (int r = 0; r < 8; ++r) {
                float o = so[r * 128 + k];
                accL[r] += o * wL;
                accR[r] += o * wR;
            }
        }
        float bb = gb1[t];
        #pragma unroll
        for (int r = 0; r < 8; ++r) {
            int row = r0 + r;
            Lh[row * 256 + t] = (_Float16)(accL[r] + bb);
            *(_Float16*)(RhB + row * 512 + ((2 * t) ^ ((row & 15) << 4))) = (_Float16)accR[r];
        }
    } else if (blk < 272) {
        const int tb = blk - 256;
        const int k0 = (tb >> 2) * 64, c0 = (tb & 3) * 64;
        for (int it = 0; it < 16; ++it) {
            int idx = it * 256 + t, rr = idx >> 6, cc = idx & 63;
            tt[rr * 65 + cc] = gW2[(k0 + rr) * 256 + c0 + cc];
        }
        __syncthreads();
        for (int it = 0; it < 16; ++it) {
            int idx = it * 256 + t, cr = idx >> 6, kk = idx & 63;
            W2h[(c0 + cr) * 256 + (k0 + kk)] = (_Float16)tt[kk * 65 + cr];
        }
    } else {
        for (int it = 0; it < 32; ++it) S[it * 256 + t] = 0.f;
    }
}

// ---------------------------------------------------------------------------
// Main: grid 256 = 32 b x 8 ig; 512 thr = 8 waves = (mg 2) x (ng 4).
// Wave (mg,ng): rows [mg*32,+32), cols [ng*64,+64). 8 i's per block.
// W2 slice register-resident (bfr, 128 VGPR, loaded once). Rh rows for this
// wave's 32 j-rows hoisted to regs (rh, 32 VGPR) — ii-loop re-reads ONLY the
// broadcast lh. A-frag in regs: pk_max(pk_add(lh,rh),0); mfma 16x16x32 f16.
// Column sums accumulated across 8 i's; one atomicAdd per col per wave.
// ~230 VGPR -> 2 waves/SIMD (launch_bounds(512,2)).
// ---------------------------------------------------------------------------
__global__ __launch_bounds__(512, 2) void rn_main(
    const char* __restrict__ LhB, const char* __restrict__ RhB,
    const _Float16* __restrict__ W2h, const float* __restrict__ gb2,
    float* __restrict__ S)
{
    __shared__ __attribute__((aligned(16))) char smem[36864];  // Rh 32KB + Lh 4KB
    const int blk = blockIdx.x;               // 256 = 32 b x 8 ig
    const int b = blk >> 3, ig = blk & 7;
    const int t = threadIdx.x, lane = t & 63, w = t >> 6;
    const int mg = w >> 2, ng = w & 3;
    const int lc = lane & 15, lg = lane >> 4;

    {   // stage Rh[b] (pre-swizzled, linear) + Lh rows ig*8..+8
        const char* gR = RhB + b * 32768;
        #pragma unroll
        for (int it = 0; it < 4; ++it) {
            int u = it * 512 + t;
            *(f32x4*)(smem + u * 16) = *(const f32x4*)(gR + u * 16);
        }
        if (t < 256) {
            const char* gL = LhB + (b * 64 + ig * 8) * 512;
            *(f32x4*)(smem + 32768 + t * 16) = *(const f32x4*)(gL + t * 16);
        }
    }

    // register-resident B (ii/mg-invariant): 4 n-tiles x 8 ks
    half8 bfr[4][8];
    #pragma unroll
    for (int n = 0; n < 4; ++n)
        #pragma unroll
        for (int ks = 0; ks < 8; ++ks)
            bfr[n][ks] = *(const half8*)(W2h + (ng * 64 + n * 16 + lc) * 256 + ks * 32 + lg * 8);

    float bias[4];
    #pragma unroll
    for (int n = 0; n < 4; ++n) bias[n] = gb2[ng * 64 + n * 16 + lc];

    __syncthreads();

    // hoist this wave's Rh rows into regs: 2 m-tiles x 8 ks (ii-invariant)
    half8 rh[2][8];
    #pragma unroll
    for (int m2 = 0; m2 < 2; ++m2) {
        int row = mg * 32 + m2 * 16 + lc;
        #pragma unroll
        for (int ks = 0; ks < 8; ++ks) {
            int kb = ks * 64 + lg * 16;
            rh[m2][ks] = *(const half8*)(smem + row * 512 + (kb ^ (lc << 4)));
        }
    }

    const half8 zero8 = {(_Float16)0.f, (_Float16)0.f, (_Float16)0.f, (_Float16)0.f,
                         (_Float16)0.f, (_Float16)0.f, (_Float16)0.f, (_Float16)0.f};
    float csum[4] = {0.f, 0.f, 0.f, 0.f};

    for (int ii = 0; ii < 8; ++ii) {
        f32x4 acc[2][4];
        #pragma unroll
        for (int m2 = 0; m2 < 2; ++m2)
            #pragma unroll
            for (int n = 0; n < 4; ++n)
                acc[m2][n] = (f32x4){0.f, 0.f, 0.f, 0.f};

        #pragma unroll
        for (int ks = 0; ks < 8; ++ks) {
            half8 lhv = *(const half8*)(smem + 32768 + ii * 512 + ks * 64 + lg * 16);
            #pragma unroll
            for (int m2 = 0; m2 < 2; ++m2) {
                half8 av = lhv + rh[m2][ks];                      // v_pk_add_f16
                av = __builtin_elementwise_max(av, zero8);        // v_pk_max_f16
                #pragma unroll
                for (int n = 0; n < 4; ++n)
                    acc[m2][n] = __builtin_amdgcn_mfma_f32_16x16x32_f16(
                        av, bfr[n][ks], acc[m2][n], 0, 0, 0);
            }
        }

        const int iglob = ig * 8 + ii;
        #pragma unroll
        for (int n = 0; n < 4; ++n) {
            float cs = 0.f;
            #pragma unroll
            for (int m2 = 0; m2 < 2; ++m2)
                #pragma unroll
                for (int q = 0; q < 4; ++q) {
                    int row = mg * 32 + m2 * 16 + lg * 4 + q;   // = j
                    float v = fmaxf(acc[m2][n][q] + bias[n], 0.f);
                    cs += (row == iglob) ? 0.f : v;
                }
            csum[n] += cs;
        }
    }

    #pragma unroll
    for (int n = 0; n < 4; ++n) {
        float cs = csum[n];
        cs += __shfl_xor(cs, 16);
        cs += __shfl_xor(cs, 32);
        if (lane < 16) atomicAdd(&S[b * 256 + ng * 64 + n * 16 + lc], cs);
    }
}

// ---------------------------------------------------------------------------
// Final: block per b, 1024 thr = (64 col-groups of 4) x (16 kq). Three
// chained matvecs; per phase each thread does 16 independent float4 loads
// (k-split 16-way), partials reduced via padded LDS.
// ---------------------------------------------------------------------------
__global__ __launch_bounds__(1024) void rn_final(
    const float* __restrict__ S, const float* __restrict__ gW3,
    const float* __restrict__ gb3, const float* __restrict__ fW1,
    const float* __restrict__ fb1, const float* __restrict__ fW2,
    const float* __restrict__ fb2, float* __restrict__ out)
{
    __shared__ float vec[256];
    __shared__ float ps[16][260];
    const int b = blockIdx.x, t = threadIdx.x;
    const int cg = t & 63, kq = t >> 6;
    const int c0 = cg * 4;

    if (t < 256) vec[t] = S[b * 256 + t];
    __syncthreads();

    // phase 1: agg = vec @ gW3 + 4032*gb3
    {
        f32x4 s = (f32x4){0.f, 0.f, 0.f, 0.f};
        #pragma unroll
        for (int kk = 0; kk < 16; ++kk) {
            int k = kq * 16 + kk;
            f32x4 wv = *(const f32x4*)&gW3[k * 256 + c0];
            s += wv * vec[k];
        }
        *(f32x4*)&ps[kq][c0] = s;
    }
    __syncthreads();
    if (t < 256) {
        float a = 0.f;
        #pragma unroll
        for (int q = 0; q < 16; ++q) a += ps[q][t];
        vec[t] = a + 4032.0f * gb3[t];
    }
    __syncthreads();

    // phase 2: u = relu(vec @ fW1 + fb1)
    {
        f32x4 s = (f32x4){0.f, 0.f, 0.f, 0.f};
        #pragma unroll
        for (int kk = 0; kk < 16; ++kk) {
            int k = kq * 16 + kk;
            f32x4 wv = *(const f32x4*)&fW1[k * 256 + c0];
            s += wv * vec[k];
        }
        *(f32x4*)&ps[kq][c0] = s;
    }
    __syncthreads();
    if (t < 256) {
        float a = 0.f;
        #pragma unroll
        for (int q = 0; q < 16; ++q) a += ps[q][t];
        vec[t] = fmaxf(a + fb1[t], 0.f);
    }
    __syncthreads();

    // phase 3: out = vec @ fW2 + fb2
    {
        f32x4 s = (f32x4){0.f, 0.f, 0.f, 0.f};
        #pragma unroll
        for (int kk = 0; kk < 16; ++kk) {
            int k = kq * 16 + kk;
            f32x4 wv = *(const f32x4*)&fW2[k * 256 + c0];
            s += wv * vec[k];
        }
        *(f32x4*)&ps[kq][c0] = s;
    }
    __syncthreads();
    if (t < 256) {
        float a = 0.f;
        #pragma unroll
        for (int q = 0; q < 16; ++q) a += ps[q][t];
        out[b * 256 + t] = a + fb2[t];
    }
}

extern "C" void kernel_launch(void* const* d_in, const int* in_sizes, int n_in,
                              void* d_out, int out_size, void* d_ws, size_t ws_size,
                              hipStream_t stream)
{
    const float* obj = (const float*)d_in[0];
    const float* gW1 = (const float*)d_in[1];
    const float* gb1 = (const float*)d_in[2];
    const float* gW2 = (const float*)d_in[3];
    const float* gb2 = (const float*)d_in[4];
    const float* gW3 = (const float*)d_in[5];
    const float* gb3 = (const float*)d_in[6];
    const float* fW1 = (const float*)d_in[7];
    const float* fb1 = (const float*)d_in[8];
    const float* fW2 = (const float*)d_in[9];
    const float* fb2 = (const float*)d_in[10];
    float* out = (float*)d_out;

    char* ws = (char*)d_ws;
    _Float16* Lh  = (_Float16*)(ws);                           // 1 MB
    char*     RhB = ws + (1u << 20);                           // 1 MB (swizzled fp16)
    _Float16* W2h = (_Float16*)(ws + (2u << 20));              // 128 KB
    float*    S   = (float*)(ws + (2u << 20) + (128u << 10));  // 32 KB

    rn_prep <<<273, 256, 0, stream>>>(obj, gW1, gb1, gW2, Lh, RhB, W2h, S);
    rn_main <<<256, 512, 0, stream>>>((const char*)Lh, RhB, W2h, gb2, S);
    rn_final<<<32, 1024, 0, stream>>>(S, gW3, gb3, fW1, fb1, fW2, fb2, out);
}